// Round 1
// baseline (161.641 us; speedup 1.0000x reference)
//
#include <hip/hip_runtime.h>

// Problem constants (match reference setup_inputs):
// x: (N=4, C=256, H=128, W=128) f32 NCHW; rois: (K,5) f32; out: (K,256,7,7) f32
#define NB    4
#define CCH   256
#define HH    128
#define WW    128
#define HW    (HH * WW)          // 16384
#define CHW   (CCH * HW)         // 4194304 = 1<<22
#define PBINS 49                 // 7*7
#define OUT_PER_ROI (CCH * PBINS) // 12544

// ---------------------------------------------------------------------------
// Kernel 1: NCHW -> NHWC transpose (per n: (C, HW) -> (HW, C)), 32x32 tiles
// ---------------------------------------------------------------------------
__global__ __launch_bounds__(256) void xpose_nchw_nhwc(
    const float* __restrict__ src, float* __restrict__ dst) {
  __shared__ float tile[32][33];
  const int n   = blockIdx.z;
  const int hw0 = blockIdx.x * 32;
  const int c0  = blockIdx.y * 32;
  const float* s = src + (size_t)n * CHW;
  float*       d = dst + (size_t)n * CHW;
  const int tx = threadIdx.x;  // 0..31
  const int ty = threadIdx.y;  // 0..7
#pragma unroll
  for (int i = 0; i < 32; i += 8)
    tile[ty + i][tx] = s[(size_t)(c0 + ty + i) * HW + (hw0 + tx)];
  __syncthreads();
#pragma unroll
  for (int i = 0; i < 32; i += 8)
    d[(size_t)(hw0 + ty + i) * CCH + (c0 + tx)] = tile[tx][ty + i];
}

// ---------------------------------------------------------------------------
// Kernel 2: ROI align over NHWC feature map. One block (4 waves) per ROI.
// Wave w handles bins p = w, w+4, ...; lane handles 4 consecutive channels.
// Pooled results staged in LDS laid out exactly like the output slice
// (idx = c*49 + p) so the final global write is one contiguous 50KB copy.
// ---------------------------------------------------------------------------
__global__ __launch_bounds__(256) void roi_align_nhwc(
    const float* __restrict__ xt, const float* __restrict__ rois,
    float* __restrict__ out) {
  __shared__ float s_pool[OUT_PER_ROI];   // 49 KB
  __shared__ float s_fy[14], s_fx[14];
  __shared__ int   s_y0[14], s_y1[14], s_x0[14], s_x1[14], s_vy[14], s_vx[14];

  const int k   = blockIdx.x;
  const int tid = threadIdx.x;
  const float* r = rois + 5 * k;
  const int   n  = (int)r[0];
  const float sx = r[1] * 0.0625f, sy = r[2] * 0.0625f;
  const float ex = r[3] * 0.0625f, ey = r[4] * 0.0625f;
  const float rw = fmaxf(ex - sx, 1.0f);
  const float rh = fmaxf(ey - sy, 1.0f);

  if (tid < 14) {                       // y metadata (wave 0)
    float g  = ((float)tid + 0.5f) * 0.5f;
    float v  = sy + (rh / 7.0f) * g;
    int   ok = (v > -1.0f) && (v < 128.0f);
    float vc = fminf(fmaxf(v, 0.0f), 127.0f);
    int   lo = (int)floorf(vc);
    s_y0[tid] = lo;
    s_y1[tid] = min(lo + 1, 127);
    s_fy[tid] = vc - (float)lo;
    s_vy[tid] = ok;
  } else if (tid >= 64 && tid < 78) {   // x metadata (wave 1)
    int   j  = tid - 64;
    float g  = ((float)j + 0.5f) * 0.5f;
    float v  = sx + (rw / 7.0f) * g;
    int   ok = (v > -1.0f) && (v < 128.0f);
    float vc = fminf(fmaxf(v, 0.0f), 127.0f);
    int   lo = (int)floorf(vc);
    s_x0[j] = lo;
    s_x1[j] = min(lo + 1, 127);
    s_fx[j] = vc - (float)lo;
    s_vx[j] = ok;
  }
  __syncthreads();

  const int wv   = tid >> 6;
  const int lane = tid & 63;
  const float* xbase = xt + ((size_t)n << 22) + (lane << 2);

  for (int p = wv; p < PBINS; p += 4) {
    const int ph = p / 7;
    const int pw = p - 7 * ph;
    float a0 = 0.f, a1 = 0.f, a2 = 0.f, a3 = 0.f;
#pragma unroll
    for (int iy = 0; iy < 2; ++iy) {
      const int   gy = 2 * ph + iy;
      const int   vy = s_vy[gy];
      const float fy = s_fy[gy];
      const int   y0 = s_y0[gy], y1 = s_y1[gy];
#pragma unroll
      for (int ix = 0; ix < 2; ++ix) {
        const int gx = 2 * pw + ix;
        if (vy && s_vx[gx]) {
          const float fx = s_fx[gx];
          const int   x0 = s_x0[gx], x1 = s_x1[gx];
          const float4 v00 = *(const float4*)(xbase + (y0 << 15) + (x0 << 8));
          const float4 v01 = *(const float4*)(xbase + (y0 << 15) + (x1 << 8));
          const float4 v10 = *(const float4*)(xbase + (y1 << 15) + (x0 << 8));
          const float4 v11 = *(const float4*)(xbase + (y1 << 15) + (x1 << 8));
          const float w00 = (1.f - fy) * (1.f - fx);
          const float w01 = (1.f - fy) * fx;
          const float w10 = fy * (1.f - fx);
          const float w11 = fy * fx;
          a0 += w00 * v00.x + w01 * v01.x + w10 * v10.x + w11 * v11.x;
          a1 += w00 * v00.y + w01 * v01.y + w10 * v10.y + w11 * v11.y;
          a2 += w00 * v00.z + w01 * v01.z + w10 * v10.z + w11 * v11.z;
          a3 += w00 * v00.w + w01 * v01.w + w10 * v10.w + w11 * v11.w;
        }
      }
    }
    const int cb = lane << 2;
    s_pool[(cb + 0) * PBINS + p] = a0 * 0.25f;
    s_pool[(cb + 1) * PBINS + p] = a1 * 0.25f;
    s_pool[(cb + 2) * PBINS + p] = a2 * 0.25f;
    s_pool[(cb + 3) * PBINS + p] = a3 * 0.25f;
  }
  __syncthreads();

  float* o = out + (size_t)k * OUT_PER_ROI;
  for (int i = tid; i < OUT_PER_ROI; i += 256) o[i] = s_pool[i];
}

// ---------------------------------------------------------------------------
// Fallback: direct NCHW gather, one thread per output element (used only if
// workspace is too small for the NHWC copy).
// ---------------------------------------------------------------------------
__global__ __launch_bounds__(256) void roi_align_nchw(
    const float* __restrict__ x, const float* __restrict__ rois,
    float* __restrict__ out, int total) {
  int idx = blockIdx.x * 256 + threadIdx.x;
  if (idx >= total) return;
  int k  = idx / OUT_PER_ROI;
  int rr = idx - k * OUT_PER_ROI;
  int c  = rr / PBINS;
  int p  = rr - c * PBINS;
  int ph = p / 7, pw = p - 7 * ph;
  const float* r = rois + 5 * k;
  int   n  = (int)r[0];
  float sx = r[1] * 0.0625f, sy = r[2] * 0.0625f;
  float ex = r[3] * 0.0625f, ey = r[4] * 0.0625f;
  float rw = fmaxf(ex - sx, 1.0f);
  float rh = fmaxf(ey - sy, 1.0f);
  const float* xb = x + ((size_t)n * CCH + c) * HW;
  float acc = 0.f;
  for (int iy = 0; iy < 2; ++iy) {
    float g  = (float)(2 * ph + iy) + 0.5f;
    float v  = sy + (rh / 7.0f) * (g * 0.5f);
    if (!(v > -1.0f && v < 128.0f)) continue;
    float vc = fminf(fmaxf(v, 0.0f), 127.0f);
    int   y0 = (int)floorf(vc);
    int   y1 = min(y0 + 1, 127);
    float fy = vc - (float)y0;
    for (int ix = 0; ix < 2; ++ix) {
      float gx  = (float)(2 * pw + ix) + 0.5f;
      float vx_ = sx + (rw / 7.0f) * (gx * 0.5f);
      if (!(vx_ > -1.0f && vx_ < 128.0f)) continue;
      float vcx = fminf(fmaxf(vx_, 0.0f), 127.0f);
      int   x0  = (int)floorf(vcx);
      int   x1  = min(x0 + 1, 127);
      float fx  = vcx - (float)x0;
      float v00 = xb[y0 * WW + x0], v01 = xb[y0 * WW + x1];
      float v10 = xb[y1 * WW + x0], v11 = xb[y1 * WW + x1];
      acc += v00 * (1.f - fy) * (1.f - fx) + v01 * (1.f - fy) * fx +
             v10 * fy * (1.f - fx) + v11 * fy * fx;
    }
  }
  out[idx] = acc * 0.25f;
}

extern "C" void kernel_launch(void* const* d_in, const int* in_sizes, int n_in,
                              void* d_out, int out_size, void* d_ws, size_t ws_size,
                              hipStream_t stream) {
  const float* x    = (const float*)d_in[0];
  const float* rois = (const float*)d_in[1];
  float*       out  = (float*)d_out;
  const int K = in_sizes[1] / 5;

  const size_t need = (size_t)NB * CHW * sizeof(float);  // 64 MB
  if (ws_size >= need) {
    float* xt = (float*)d_ws;
    dim3 tb(32, 8, 1);
    dim3 tg(HW / 32, CCH / 32, NB);  // 512 x 8 x 4
    xpose_nchw_nhwc<<<tg, tb, 0, stream>>>(x, xt);
    roi_align_nhwc<<<K, 256, 0, stream>>>(xt, rois, out);
  } else {
    const int total = K * OUT_PER_ROI;
    roi_align_nchw<<<(total + 255) / 256, 256, 0, stream>>>(x, rois, out, total);
  }
}

// Round 2
// 149.785 us; speedup vs baseline: 1.0792x; 1.0792x over previous
//
#include <hip/hip_runtime.h>

// x: (N=4, C=256, H=128, W=128) f32 NCHW; rois: (K,5) f32; out: (K,256,7,7) f32
#define NB    4
#define CCH   256
#define HH    128
#define WW    128
#define HW    (HH * WW)           // 16384
#define CHW   (CCH * HW)          // 4194304 = 1<<22
#define PBINS 49                  // 7*7
#define OUT_PER_ROI (CCH * PBINS) // 12544

// ---------------------------------------------------------------------------
// Kernel 1: NCHW -> NHWC transpose, 64x64 f32 tiles, float4 on both global
// sides, scalar LDS with [64][65] padding (2-way bank aliasing = free).
// ---------------------------------------------------------------------------
__global__ __launch_bounds__(256) void xpose_nchw_nhwc(
    const float* __restrict__ src, float* __restrict__ dst) {
  __shared__ float tile[64][65];
  const int n   = blockIdx.z;
  const int hw0 = blockIdx.x * 64;
  const int c0  = blockIdx.y * 64;
  const float* s = src + (size_t)n * CHW;
  float*       d = dst + (size_t)n * CHW;
  const int tx = threadIdx.x;  // 0..15  (float4 column group)
  const int ty = threadIdx.y;  // 0..15  (row base)

#pragma unroll
  for (int r = 0; r < 4; ++r) {
    const int c = ty + 16 * r;                       // 0..63
    const float4 v =
        *(const float4*)(s + (size_t)(c0 + c) * HW + hw0 + 4 * tx);
    tile[c][4 * tx + 0] = v.x;
    tile[c][4 * tx + 1] = v.y;
    tile[c][4 * tx + 2] = v.z;
    tile[c][4 * tx + 3] = v.w;
  }
  __syncthreads();
#pragma unroll
  for (int r = 0; r < 4; ++r) {
    const int h = ty + 16 * r;                       // 0..63
    float4 v;
    v.x = tile[4 * tx + 0][h];
    v.y = tile[4 * tx + 1][h];
    v.z = tile[4 * tx + 2][h];
    v.w = tile[4 * tx + 3][h];
    *(float4*)(d + (size_t)(hw0 + h) * CCH + c0 + 4 * tx) = v;
  }
}

// ---------------------------------------------------------------------------
// Kernel 2: ROI align over NHWC map. One block (512 thr = 8 waves) per ROI.
// Wave w handles bins p = w, w+8, ...; each wave covers all 256 channels
// (lane -> 4 consecutive channels, float4 gathers). Results staged in LDS
// in output layout (c*49+p) so the final store is one contiguous copy.
// ---------------------------------------------------------------------------
__global__ __launch_bounds__(512) void roi_align_nhwc(
    const float* __restrict__ xt, const float* __restrict__ rois,
    float* __restrict__ out) {
  __shared__ float s_pool[OUT_PER_ROI];   // 49 KB
  __shared__ float s_fy[14], s_fx[14];
  __shared__ int   s_y0[14], s_y1[14], s_x0[14], s_x1[14], s_vy[14], s_vx[14];

  const int k   = blockIdx.x;
  const int tid = threadIdx.x;
  const float* r = rois + 5 * k;
  const int   n  = (int)r[0];
  const float sx = r[1] * 0.0625f, sy = r[2] * 0.0625f;
  const float ex = r[3] * 0.0625f, ey = r[4] * 0.0625f;
  const float rw = fmaxf(ex - sx, 1.0f);
  const float rh = fmaxf(ey - sy, 1.0f);

  if (tid < 14) {                       // y metadata
    float g  = ((float)tid + 0.5f) * 0.5f;
    float v  = sy + (rh / 7.0f) * g;
    int   ok = (v > -1.0f) && (v < 128.0f);
    float vc = fminf(fmaxf(v, 0.0f), 127.0f);
    int   lo = (int)floorf(vc);
    s_y0[tid] = lo;
    s_y1[tid] = min(lo + 1, 127);
    s_fy[tid] = vc - (float)lo;
    s_vy[tid] = ok;
  } else if (tid >= 64 && tid < 78) {   // x metadata
    int   j  = tid - 64;
    float g  = ((float)j + 0.5f) * 0.5f;
    float v  = sx + (rw / 7.0f) * g;
    int   ok = (v > -1.0f) && (v < 128.0f);
    float vc = fminf(fmaxf(v, 0.0f), 127.0f);
    int   lo = (int)floorf(vc);
    s_x0[j] = lo;
    s_x1[j] = min(lo + 1, 127);
    s_fx[j] = vc - (float)lo;
    s_vx[j] = ok;
  }
  __syncthreads();

  const int wv   = tid >> 6;            // 0..7
  const int lane = tid & 63;
  const float* xbase = xt + ((size_t)n << 22) + (lane << 2);

  for (int p = wv; p < PBINS; p += 8) {
    const int ph = p / 7;
    const int pw = p - 7 * ph;
    float a0 = 0.f, a1 = 0.f, a2 = 0.f, a3 = 0.f;
#pragma unroll
    for (int iy = 0; iy < 2; ++iy) {
      const int   gy = 2 * ph + iy;
      const int   vy = s_vy[gy];
      const float fy = s_fy[gy];
      const int   y0 = s_y0[gy], y1 = s_y1[gy];
#pragma unroll
      for (int ix = 0; ix < 2; ++ix) {
        const int gx = 2 * pw + ix;
        if (vy && s_vx[gx]) {
          const float fx = s_fx[gx];
          const int   x0 = s_x0[gx], x1 = s_x1[gx];
          const float4 v00 = *(const float4*)(xbase + (y0 << 15) + (x0 << 8));
          const float4 v01 = *(const float4*)(xbase + (y0 << 15) + (x1 << 8));
          const float4 v10 = *(const float4*)(xbase + (y1 << 15) + (x0 << 8));
          const float4 v11 = *(const float4*)(xbase + (y1 << 15) + (x1 << 8));
          const float w00 = (1.f - fy) * (1.f - fx);
          const float w01 = (1.f - fy) * fx;
          const float w10 = fy * (1.f - fx);
          const float w11 = fy * fx;
          a0 += w00 * v00.x + w01 * v01.x + w10 * v10.x + w11 * v11.x;
          a1 += w00 * v00.y + w01 * v01.y + w10 * v10.y + w11 * v11.y;
          a2 += w00 * v00.z + w01 * v01.z + w10 * v10.z + w11 * v11.z;
          a3 += w00 * v00.w + w01 * v01.w + w10 * v10.w + w11 * v11.w;
        }
      }
    }
    const int cb = lane << 2;
    s_pool[(cb + 0) * PBINS + p] = a0 * 0.25f;
    s_pool[(cb + 1) * PBINS + p] = a1 * 0.25f;
    s_pool[(cb + 2) * PBINS + p] = a2 * 0.25f;
    s_pool[(cb + 3) * PBINS + p] = a3 * 0.25f;
  }
  __syncthreads();

  float* o = out + (size_t)k * OUT_PER_ROI;
  for (int i = tid; i < OUT_PER_ROI; i += 512) o[i] = s_pool[i];
}

// ---------------------------------------------------------------------------
// Fallback: direct NCHW gather (only if workspace too small).
// ---------------------------------------------------------------------------
__global__ __launch_bounds__(256) void roi_align_nchw(
    const float* __restrict__ x, const float* __restrict__ rois,
    float* __restrict__ out, int total) {
  int idx = blockIdx.x * 256 + threadIdx.x;
  if (idx >= total) return;
  int k  = idx / OUT_PER_ROI;
  int rr = idx - k * OUT_PER_ROI;
  int c  = rr / PBINS;
  int p  = rr - c * PBINS;
  int ph = p / 7, pw = p - 7 * ph;
  const float* r = rois + 5 * k;
  int   n  = (int)r[0];
  float sx = r[1] * 0.0625f, sy = r[2] * 0.0625f;
  float ex = r[3] * 0.0625f, ey = r[4] * 0.0625f;
  float rw = fmaxf(ex - sx, 1.0f);
  float rh = fmaxf(ey - sy, 1.0f);
  const float* xb = x + ((size_t)n * CCH + c) * HW;
  float acc = 0.f;
  for (int iy = 0; iy < 2; ++iy) {
    float g  = (float)(2 * ph + iy) + 0.5f;
    float v  = sy + (rh / 7.0f) * (g * 0.5f);
    if (!(v > -1.0f && v < 128.0f)) continue;
    float vc = fminf(fmaxf(v, 0.0f), 127.0f);
    int   y0 = (int)floorf(vc);
    int   y1 = min(y0 + 1, 127);
    float fy = vc - (float)y0;
    for (int ix = 0; ix < 2; ++ix) {
      float gx  = (float)(2 * pw + ix) + 0.5f;
      float vx_ = sx + (rw / 7.0f) * (gx * 0.5f);
      if (!(vx_ > -1.0f && vx_ < 128.0f)) continue;
      float vcx = fminf(fmaxf(vx_, 0.0f), 127.0f);
      int   x0  = (int)floorf(vcx);
      int   x1  = min(x0 + 1, 127);
      float fx  = vcx - (float)x0;
      float v00 = xb[y0 * WW + x0], v01 = xb[y0 * WW + x1];
      float v10 = xb[y1 * WW + x0], v11 = xb[y1 * WW + x1];
      acc += v00 * (1.f - fy) * (1.f - fx) + v01 * (1.f - fy) * fx +
             v10 * fy * (1.f - fx) + v11 * fy * fx;
    }
  }
  out[idx] = acc * 0.25f;
}

extern "C" void kernel_launch(void* const* d_in, const int* in_sizes, int n_in,
                              void* d_out, int out_size, void* d_ws, size_t ws_size,
                              hipStream_t stream) {
  const float* x    = (const float*)d_in[0];
  const float* rois = (const float*)d_in[1];
  float*       out  = (float*)d_out;
  const int K = in_sizes[1] / 5;

  const size_t need = (size_t)NB * CHW * sizeof(float);  // 64 MB
  if (ws_size >= need) {
    float* xt = (float*)d_ws;
    dim3 tb(16, 16, 1);
    dim3 tg(HW / 64, CCH / 64, NB);  // 256 x 4 x 4
    xpose_nchw_nhwc<<<tg, tb, 0, stream>>>(x, xt);
    roi_align_nhwc<<<K, 512, 0, stream>>>(xt, rois, out);
  } else {
    const int total = K * OUT_PER_ROI;
    roi_align_nchw<<<(total + 255) / 256, 256, 0, stream>>>(x, rois, out, total);
  }
}